// Round 8
// baseline (229.330 us; speedup 1.0000x reference)
//
#include <hip/hip_runtime.h>
#include <math.h>

#define N_TOK 16384
#define HDIM  2048
#define NEXP  64
#define TOPK  8
#define NKS   4             // K split factor
#define KSEG  (HDIM / NKS)  // 512 k per block

// d_ws layout:
//   [0, 32 MiB)       : part  — partial logits f64 [NKS][N_TOK][64]
//   [32 MiB, 33 MiB)  : Wt    — weight transposed f64 [2048 k][64 e]
//   [33 MiB, ...)     : stats — f32 probsum[64], counts[64], then int flag
#define PART_OFF  0
#define WT_OFF    (32u << 20)
#define STATS_OFF (33u << 20)

typedef double d4 __attribute__((ext_vector_type(4)));

// Wt[k][e] = (double)W[e][k]; writes coalesced, reads L2-cached.
__global__ __launch_bounds__(256) void conv_wt_kernel(const float* __restrict__ W,
                                                      double* __restrict__ Wt) {
    int i = blockIdx.x * 256 + threadIdx.x;          // grid 512*256 = 131072
    int k = i >> 6, e = i & 63;
    Wt[i] = (double)W[(size_t)e * HDIM + k];
}

// In-band MFMA layout verification (1 wave). Asymmetric integer A (16x4),
// B (4x16); exact f64 reference per lane. H1 = documented mapping
// (A: row=l&15,k=l>>4; B: k=l>>4,col=l&15; D: row=(l>>4)*4+r, col=l&15).
// H2 = same feeds, transposed output. flag = 1 (H1) / 2 (H2) / 0 (neither).
__global__ void mfma_probe_kernel(int* __restrict__ flag) {
    const int l   = threadIdx.x;
    const int i16 = l & 15, q = l >> 4;
    double a = (double)(i16 * 4 + q + 1);            // A[i16][q]
    double b = (double)((q + 1) * 100 + 3 * i16);    // B[q][i16]
    d4 acc = {0., 0., 0., 0.};
    acc = __builtin_amdgcn_mfma_f64_16x16x4f64(a, b, acc, 0, 0, 0);
    int ok1 = 1, ok2 = 1;
#pragma unroll
    for (int r = 0; r < 4; ++r) {
        const int row = q * 4 + r, col = i16;
        double d1 = 0.0, d2 = 0.0;
#pragma unroll
        for (int k = 0; k < 4; ++k) {
            d1 += (double)(row * 4 + k + 1) * (double)((k + 1) * 100 + 3 * col);
            d2 += (double)(col * 4 + k + 1) * (double)((k + 1) * 100 + 3 * row);
        }
        ok1 &= (acc[r] == d1);                       // H1: D[row][col]
        ok2 &= (acc[r] == d2);                       // H2: D[col][row]
    }
    ok1 = __all(ok1); ok2 = __all(ok2);
    if (l == 0) *flag = ok1 ? 1 : (ok2 ? 2 : 0);
}

// MFMA f64 GEMM. Runs only if flag != 0. Block 256 thr = 4 waves (2x2):
// wave (wr,wc) -> 32 tok x 32 exp as 2x2 16x16 frags. Tile 64 tok x 64 exp
// x 512 k. Grid 1024 (256 tt x 4 ks) = 4 blocks/CU. X f32->f64 staged in
// LDS; Wt f64 staged in LDS; feed = 4 ds_read_b64 per 4 MFMA (8192 FLOP).
__global__ __launch_bounds__(256) void gemm_mfma_kernel(const float* __restrict__ X,
                                                        const double* __restrict__ Wt,
                                                        const int* __restrict__ flag,
                                                        double* __restrict__ part) {
    const int f = *flag;
    if (f == 0) return;                              // layout unverified -> VALU path
    const int tt  = blockIdx.x >> 2;
    const int ks  = blockIdx.x & 3;
    const int tid = threadIdx.x;
    const int l   = tid & 63;
    const int wv  = tid >> 6;
    const int wr  = wv >> 1, wc = wv & 1;
    const int tok0 = tt * 64;
    const int k0   = ks * KSEG;

    __shared__ double xs[64][34];                    // 64 tok x 32 k (+2 pad)
    __shared__ double wsh[32][66];                   // 32 k x 64 exp (+2 pad)

    d4 acc[2][2];
#pragma unroll
    for (int i = 0; i < 2; ++i)
#pragma unroll
        for (int j = 0; j < 2; ++j) acc[i][j] = (d4){0., 0., 0., 0.};

    // staging coords
    const int xr = tid >> 2;                         // 0..63 token row
    const int xc = (tid & 3) * 8;                    // 8 floats each
    const float* xg = X + (size_t)(tok0 + xr) * HDIM + k0 + xc;
    const int wk = tid >> 3;                         // 0..31 k row
    const int we = (tid & 7) * 8;                    // 8 doubles each
    const double* wg = Wt + (size_t)(k0 + wk) * NEXP + we;

    float4  px0 = *(const float4*)xg;
    float4  px1 = *(const float4*)(xg + 4);
    double2 pw0 = *(const double2*)(wg);
    double2 pw1 = *(const double2*)(wg + 2);
    double2 pw2 = *(const double2*)(wg + 4);
    double2 pw3 = *(const double2*)(wg + 6);

    for (int c = 0; c < KSEG / 32; ++c) {            // 16 chunks of 32 k
        __syncthreads();
        {
            double2 t;
            t.x = (double)px0.x; t.y = (double)px0.y; *(double2*)&xs[xr][xc]     = t;
            t.x = (double)px0.z; t.y = (double)px0.w; *(double2*)&xs[xr][xc + 2] = t;
            t.x = (double)px1.x; t.y = (double)px1.y; *(double2*)&xs[xr][xc + 4] = t;
            t.x = (double)px1.z; t.y = (double)px1.w; *(double2*)&xs[xr][xc + 6] = t;
            *(double2*)&wsh[wk][we]     = pw0;
            *(double2*)&wsh[wk][we + 2] = pw1;
            *(double2*)&wsh[wk][we + 4] = pw2;
            *(double2*)&wsh[wk][we + 6] = pw3;
        }
        __syncthreads();
        if (c + 1 < KSEG / 32) {                     // prefetch next chunk
            const float*  xn = xg + (c + 1) * 32;
            const double* wn = wg + (size_t)(c + 1) * 32 * NEXP;
            px0 = *(const float4*)xn;
            px1 = *(const float4*)(xn + 4);
            pw0 = *(const double2*)(wn);
            pw1 = *(const double2*)(wn + 2);
            pw2 = *(const double2*)(wn + 4);
            pw3 = *(const double2*)(wn + 6);
        }
#pragma unroll
        for (int kq = 0; kq < 8; ++kq) {             // 8 K=4 steps
            const int krow = kq * 4 + (l >> 4);
            double a0 = xs[wr * 32 + (l & 15)][krow];
            double a1 = xs[wr * 32 + 16 + (l & 15)][krow];
            double b0 = wsh[krow][wc * 32 + (l & 15)];
            double b1 = wsh[krow][wc * 32 + 16 + (l & 15)];
            acc[0][0] = __builtin_amdgcn_mfma_f64_16x16x4f64(a0, b0, acc[0][0], 0, 0, 0);
            acc[0][1] = __builtin_amdgcn_mfma_f64_16x16x4f64(a0, b1, acc[0][1], 0, 0, 0);
            acc[1][0] = __builtin_amdgcn_mfma_f64_16x16x4f64(a1, b0, acc[1][0], 0, 0, 0);
            acc[1][1] = __builtin_amdgcn_mfma_f64_16x16x4f64(a1, b1, acc[1][1], 0, 0, 0);
        }
    }

    double* pbase = part + (size_t)ks * N_TOK * NEXP;
#pragma unroll
    for (int rt = 0; rt < 2; ++rt)
#pragma unroll
        for (int ct = 0; ct < 2; ++ct)
#pragma unroll
            for (int r = 0; r < 4; ++r) {
                int tok, ex;
                if (f == 1) {                        // H1: row=(l>>4)*4+r, col=l&15
                    tok = tok0 + wr * 32 + rt * 16 + (l >> 4) * 4 + r;
                    ex  = wc * 32 + ct * 16 + (l & 15);
                } else {                             // H2: transposed output
                    tok = tok0 + wr * 32 + rt * 16 + (l & 15);
                    ex  = wc * 32 + ct * 16 + (l >> 4) * 4 + r;
                }
                pbase[(size_t)tok * NEXP + ex] = acc[rt][ct][r];
            }
}

// VALU fallback (R7 kernel, proven absmax 0). Runs only if flag == 0.
__global__ __launch_bounds__(512, 4) void gemm_valu_kernel(const float* __restrict__ X,
                                                           const double* __restrict__ Wt,
                                                           const int* __restrict__ flag,
                                                           double* __restrict__ part) {
    if (*flag != 0) return;                          // MFMA path verified -> skip
    const int tt   = blockIdx.x >> 2;
    const int ks   = blockIdx.x & 3;
    const int tid  = threadIdx.x;
    const int lane = tid & 63;                       // expert
    const int wv   = tid >> 6;                       // 0..7
    const int tok0 = tt * 64;
    const int k0   = ks * KSEG;

    __shared__ double xs[64][18];
    __shared__ double wsh[16][66];

    double acc[8];
#pragma unroll
    for (int t = 0; t < 8; ++t) acc[t] = 0.0;

    const int sx_tok = tid >> 3;
    const int sx_k   = (tid & 7) * 2;
    const float* xg  = X + (size_t)(tok0 + sx_tok) * HDIM + k0 + sx_k;
    const int sw_k = tid >> 5;
    const int sw_e = (tid & 31) * 2;
    const double* wg = Wt + (size_t)(k0 + sw_k) * NEXP + sw_e;

    float2  px = *(const float2*)xg;
    double2 pw = *(const double2*)wg;

    for (int c = 0; c < KSEG / 16; ++c) {
        __syncthreads();
        {
            double2 xv; xv.x = (double)px.x; xv.y = (double)px.y;
            *(double2*)&xs[sx_tok][sx_k] = xv;
            *(double2*)&wsh[sw_k][sw_e]  = pw;
        }
        __syncthreads();
        if (c + 1 < KSEG / 16) {
            px = *(const float2*)(xg + (c + 1) * 16);
            pw = *(const double2*)(wg + (size_t)(c + 1) * 16 * NEXP);
        }
        double wr_[16];
#pragma unroll
        for (int j = 0; j < 16; ++j) wr_[j] = wsh[j][lane];
#pragma unroll
        for (int t = 0; t < 8; ++t) {
            const int tr = wv * 8 + t;
#pragma unroll
            for (int kp = 0; kp < 8; ++kp) {
                double2 xv = *(const double2*)&xs[tr][kp * 2];
                acc[t] = fma(xv.x, wr_[kp * 2],     acc[t]);
                acc[t] = fma(xv.y, wr_[kp * 2 + 1], acc[t]);
            }
        }
    }

    double* pb = part + ((size_t)ks * N_TOK + tok0 + wv * 8) * NEXP + lane;
#pragma unroll
    for (int t = 0; t < 8; ++t)
        pb[(size_t)t * NEXP] = acc[t];
}

// Top-k (R7 verbatim): coalesced stage -> proven f32-score argmax ladder.
__global__ __launch_bounds__(256) void topk_kernel(const double* __restrict__ part,
                                                   float* __restrict__ outIdx,
                                                   float* __restrict__ outW,
                                                   float* __restrict__ stats) {
    __shared__ float sc_s[32][65];
    __shared__ float lds_counts[NEXP];
    __shared__ float psum_part[4][NEXP];
    const int tid  = threadIdx.x;
    const int lane = tid & 63;
    const int w    = tid >> 6;
    if (tid < NEXP) lds_counts[tid] = 0.f;

    const int t0 = blockIdx.x * 32;
#pragma unroll
    for (int p = 0; p < 8; ++p) {
        const int idx = p * 256 + tid;
        const int t   = idx >> 6;
        const int e   = idx & 63;
        const double* pp = part + ((size_t)(t0 + t)) * NEXP + e;
        double l = (pp[0] + pp[(size_t)N_TOK * NEXP]) +
                   (pp[2 * (size_t)N_TOK * NEXP] + pp[3 * (size_t)N_TOK * NEXP]);
        sc_s[t][e] = (float)(1.0 / (1.0 + exp(-l)));
    }
    __syncthreads();

    float ps = 0.f;
    for (int i = 0; i < 8; ++i) {
        const int tloc = w * 8 + i;
        const int t    = t0 + tloc;
        float s = sc_s[tloc][lane];

        float rs = s;
#pragma unroll
        for (int off = 32; off; off >>= 1) rs += __shfl_xor(rs, off);
        ps += s / (rs + 1e-9f);

        float cur = s;
        float denom = 0.f;
        int   wi = 0;
        float wv = 0.f;
#pragma unroll
        for (int k = 0; k < TOPK; ++k) {
            float m = cur; int mi = lane;
#pragma unroll
            for (int off = 32; off; off >>= 1) {
                float om = __shfl_xor(m, off);
                int   oi = __shfl_xor(mi, off);
                if (om > m || (om == m && oi < mi)) { m = om; mi = oi; }
            }
            denom += m;
            if (lane == k)  { wi = mi; wv = m; }
            if (lane == mi) cur = -1e30f;
        }
        if (lane < TOPK) {
            outIdx[(size_t)t * TOPK + lane] = (float)wi;
            outW  [(size_t)t * TOPK + lane] = wv / (denom + 1e-9f);
            atomicAdd(&lds_counts[wi], 1.f);
        }
    }
    psum_part[w][lane] = ps;
    __syncthreads();
    if (tid < NEXP) {
        float tot = psum_part[0][tid] + psum_part[1][tid] +
                    psum_part[2][tid] + psum_part[3][tid];
        atomicAdd(&stats[tid], tot);
        atomicAdd(&stats[NEXP + tid], lds_counts[tid]);
    }
}

__global__ void aux_kernel(const float* __restrict__ stats, float* __restrict__ out) {
    const int e = threadIdx.x;
    float prob = stats[e] / (float)N_TOK;
    float cnt  = stats[NEXP + e];
    float loadf = cnt / ((float)N_TOK * TOPK);
    float S = prob;
#pragma unroll
    for (int off = 32; off; off >>= 1) S += __shfl_xor(S, off);
    float pn = prob / (S + 1e-9f);
    float v  = loadf * pn;
#pragma unroll
    for (int off = 32; off; off >>= 1) v += __shfl_xor(v, off);
    if (e == 0) out[2 * N_TOK * TOPK] = 0.001f * v * (float)NEXP;
}

extern "C" void kernel_launch(void* const* d_in, const int* in_sizes, int n_in,
                              void* d_out, int out_size, void* d_ws, size_t ws_size,
                              hipStream_t stream) {
    (void)in_sizes; (void)n_in; (void)out_size; (void)ws_size;
    const float* X = (const float*)d_in[0];
    const float* W = (const float*)d_in[1];
    float* out = (float*)d_out;
    char*  ws  = (char*)d_ws;
    double* part  = (double*)(ws + PART_OFF);
    double* Wt    = (double*)(ws + WT_OFF);
    float*  stats = (float*)(ws + STATS_OFF);
    int*    flag  = (int*)(stats + 128);

    hipMemsetAsync(stats, 0, 132 * sizeof(float), stream);
    conv_wt_kernel<<<512, 256, 0, stream>>>(W, Wt);
    mfma_probe_kernel<<<1, 64, 0, stream>>>(flag);
    gemm_mfma_kernel<<<1024, 256, 0, stream>>>(X, Wt, flag, part);
    gemm_valu_kernel<<<1024, 512, 0, stream>>>(X, Wt, flag, part);
    topk_kernel<<<512, 256, 0, stream>>>(part, out, out + N_TOK * TOPK, stats);
    aux_kernel<<<1, 64, 0, stream>>>(stats, out);
}

// Round 9
// 148.516 us; speedup vs baseline: 1.5441x; 1.5441x over previous
//
#include <hip/hip_runtime.h>
#include <math.h>

#define N_TOK 16384
#define HDIM  2048
#define NEXP  64
#define TOPK  8
#define NKS   4             // K split factor
#define KSEG  (HDIM / NKS)  // 512 k per block

// d_ws layout:
//   [0, 32 MiB)       : part  — partial logits f64 [NKS][N_TOK][64]
//   [32 MiB, 33 MiB)  : Wt    — weight transposed f64 [2048 k][64 e]
//   [33 MiB, ...)     : stats — f32 probsum[64], counts[64], then int flag
#define PART_OFF  0
#define WT_OFF    (32u << 20)
#define STATS_OFF (33u << 20)

typedef double d4 __attribute__((ext_vector_type(4)));

// Wt[k][e] = (double)W[e][k]; writes coalesced, reads L2-cached.
__global__ __launch_bounds__(256) void conv_wt_kernel(const float* __restrict__ W,
                                                      double* __restrict__ Wt) {
    int i = blockIdx.x * 256 + threadIdx.x;          // grid 512*256 = 131072
    int k = i >> 6, e = i & 63;
    Wt[i] = (double)W[(size_t)e * HDIM + k];
}

// 16-hypothesis MFMA layout probe (1 wave), exact integer arithmetic.
// A-feed ai: 0 -> (row=l&15, k=l>>4), 1 -> (row=l>>2, k=l&3)
// B-feed bi: 0 -> (k=l>>4, col=l&15), 1 -> (k=l&3, col=l>>2)
// D-read:   sf (spread form): 0 -> 4q+r, 1 -> q+4r;  tr: transpose bit.
// flag = 1 + ai*8 + bi*4 + sf*2 + tr, or 0 if none match.
__global__ void mfma_probe_kernel(int* __restrict__ flag) {
    const int l = threadIdx.x;
    const int i16 = l & 15, q = l >> 4;
    const int r4 = l >> 2,  m4 = l & 3;
    int fv = 0;
#pragma unroll
    for (int ai = 0; ai < 2; ++ai)
#pragma unroll
    for (int bi = 0; bi < 2; ++bi) {
        const int ra = ai ? r4 : i16, ka = ai ? m4 : q;
        const int cb = bi ? r4 : i16, kb = bi ? m4 : q;
        double a = (double)(ra * 4 + ka + 1);            // A[ra][ka]
        double b = (double)((kb + 1) * 100 + 3 * cb);    // B[kb][cb]
        d4 acc = {0., 0., 0., 0.};
        acc = __builtin_amdgcn_mfma_f64_16x16x4f64(a, b, acc, 0, 0, 0);
#pragma unroll
        for (int sf = 0; sf < 2; ++sf)
#pragma unroll
        for (int tr = 0; tr < 2; ++tr) {
            int ok = 1;
#pragma unroll
            for (int r = 0; r < 4; ++r) {
                const int p   = sf ? (q + 4 * r) : (4 * q + r);
                const int row = tr ? i16 : p;
                const int col = tr ? p : i16;
                double ref = 0.0;
#pragma unroll
                for (int k = 0; k < 4; ++k)
                    ref += (double)(row * 4 + k + 1) * (double)((k + 1) * 100 + 3 * col);
                ok &= (acc[r] == ref);
            }
            if (__all(ok) && fv == 0) fv = 1 + ai * 8 + bi * 4 + sf * 2 + tr;
        }
    }
    if (l == 0) *flag = fv;
}

// MFMA f64 GEMM, flag-parameterized feeds/epilogue (runs only if flag != 0).
// Block 256 thr = 4 waves (2x2): wave (wr,wc) -> 32 tok x 32 exp as 2x2
// 16x16 frags. Tile 64 tok x 64 exp x 512 k. Grid 1024 (256 tt x 4 ks).
__global__ __launch_bounds__(256) void gemm_mfma_kernel(const float* __restrict__ X,
                                                        const double* __restrict__ Wt,
                                                        const int* __restrict__ flag,
                                                        double* __restrict__ part) {
    const int f = *flag;
    if (f == 0) return;                              // layout unresolved -> VALU path
    const int fb = f - 1;
    const int ai = (fb >> 3) & 1, bi = (fb >> 2) & 1;
    const int sf = (fb >> 1) & 1, tr = fb & 1;

    const int tt  = blockIdx.x >> 2;
    const int ks  = blockIdx.x & 3;
    const int tid = threadIdx.x;
    const int l   = tid & 63;
    const int wv  = tid >> 6;
    const int wr  = wv >> 1, wc = wv & 1;
    const int tok0 = tt * 64;
    const int k0   = ks * KSEG;

    const int i16 = l & 15, q = l >> 4, r4 = l >> 2, m4 = l & 3;
    const int ra = ai ? r4 : i16, ka = ai ? m4 : q;  // A element this lane feeds
    const int cb = bi ? r4 : i16, kb = bi ? m4 : q;  // B element this lane feeds

    __shared__ double xs[64][34];                    // 64 tok x 32 k (+2 pad)
    __shared__ double wsh[32][66];                   // 32 k x 64 exp (+2 pad)

    d4 acc[2][2];
#pragma unroll
    for (int i = 0; i < 2; ++i)
#pragma unroll
        for (int j = 0; j < 2; ++j) acc[i][j] = (d4){0., 0., 0., 0.};

    // staging coords
    const int xr = tid >> 2;                         // 0..63 token row
    const int xc = (tid & 3) * 8;                    // 8 floats each
    const float* xg = X + (size_t)(tok0 + xr) * HDIM + k0 + xc;
    const int wk = tid >> 3;                         // 0..31 k row
    const int we = (tid & 7) * 8;                    // 8 doubles each
    const double* wg = Wt + (size_t)(k0 + wk) * NEXP + we;

    float4  px0 = *(const float4*)xg;
    float4  px1 = *(const float4*)(xg + 4);
    double2 pw0 = *(const double2*)(wg);
    double2 pw1 = *(const double2*)(wg + 2);
    double2 pw2 = *(const double2*)(wg + 4);
    double2 pw3 = *(const double2*)(wg + 6);

    // flag-derived fragment read pointers (k advances by 4 per MFMA step)
    const double* pa0 = &xs[wr * 32 + ra][ka];
    const double* pa1 = &xs[wr * 32 + 16 + ra][ka];
    const double* pb0 = &wsh[kb][wc * 32 + cb];
    const double* pb1 = &wsh[kb][wc * 32 + 16 + cb];

    for (int c = 0; c < KSEG / 32; ++c) {            // 16 chunks of 32 k
        __syncthreads();
        {
            double2 t;
            t.x = (double)px0.x; t.y = (double)px0.y; *(double2*)&xs[xr][xc]     = t;
            t.x = (double)px0.z; t.y = (double)px0.w; *(double2*)&xs[xr][xc + 2] = t;
            t.x = (double)px1.x; t.y = (double)px1.y; *(double2*)&xs[xr][xc + 4] = t;
            t.x = (double)px1.z; t.y = (double)px1.w; *(double2*)&xs[xr][xc + 6] = t;
            *(double2*)&wsh[wk][we]     = pw0;
            *(double2*)&wsh[wk][we + 2] = pw1;
            *(double2*)&wsh[wk][we + 4] = pw2;
            *(double2*)&wsh[wk][we + 6] = pw3;
        }
        __syncthreads();
        if (c + 1 < KSEG / 32) {                     // prefetch next chunk
            const float*  xn = xg + (c + 1) * 32;
            const double* wn = wg + (size_t)(c + 1) * 32 * NEXP;
            px0 = *(const float4*)xn;
            px1 = *(const float4*)(xn + 4);
            pw0 = *(const double2*)(wn);
            pw1 = *(const double2*)(wn + 2);
            pw2 = *(const double2*)(wn + 4);
            pw3 = *(const double2*)(wn + 6);
        }
#pragma unroll
        for (int kq = 0; kq < 8; ++kq) {             // 8 K=4 steps
            double a0 = pa0[kq * 4];                 // xs row-stride 34, k fast
            double a1 = pa1[kq * 4];
            double b0 = pb0[(size_t)kq * 4 * 66];    // wsh k-stride 66
            double b1 = pb1[(size_t)kq * 4 * 66];
            acc[0][0] = __builtin_amdgcn_mfma_f64_16x16x4f64(a0, b0, acc[0][0], 0, 0, 0);
            acc[0][1] = __builtin_amdgcn_mfma_f64_16x16x4f64(a0, b1, acc[0][1], 0, 0, 0);
            acc[1][0] = __builtin_amdgcn_mfma_f64_16x16x4f64(a1, b0, acc[1][0], 0, 0, 0);
            acc[1][1] = __builtin_amdgcn_mfma_f64_16x16x4f64(a1, b1, acc[1][1], 0, 0, 0);
        }
    }

    double* pbase = part + (size_t)ks * N_TOK * NEXP;
#pragma unroll
    for (int rt = 0; rt < 2; ++rt)
#pragma unroll
        for (int ct = 0; ct < 2; ++ct)
#pragma unroll
            for (int r = 0; r < 4; ++r) {
                const int p    = sf ? (q + 4 * r) : (4 * q + r);
                const int dtok = tr ? i16 : p;
                const int dex  = tr ? p : i16;
                const int tok  = tok0 + wr * 32 + rt * 16 + dtok;
                const int ex   = wc * 32 + ct * 16 + dex;
                pbase[(size_t)tok * NEXP + ex] = acc[rt][ct][r];
            }
}

// VALU fallback (R7 kernel, proven absmax 0). Runs only if flag == 0.
__global__ __launch_bounds__(512, 4) void gemm_valu_kernel(const float* __restrict__ X,
                                                           const double* __restrict__ Wt,
                                                           const int* __restrict__ flag,
                                                           double* __restrict__ part) {
    if (*flag != 0) return;                          // MFMA path verified -> skip
    const int tt   = blockIdx.x >> 2;
    const int ks   = blockIdx.x & 3;
    const int tid  = threadIdx.x;
    const int lane = tid & 63;                       // expert
    const int wv   = tid >> 6;                       // 0..7
    const int tok0 = tt * 64;
    const int k0   = ks * KSEG;

    __shared__ double xs[64][18];
    __shared__ double wsh[16][66];

    double acc[8];
#pragma unroll
    for (int t = 0; t < 8; ++t) acc[t] = 0.0;

    const int sx_tok = tid >> 3;
    const int sx_k   = (tid & 7) * 2;
    const float* xg  = X + (size_t)(tok0 + sx_tok) * HDIM + k0 + sx_k;
    const int sw_k = tid >> 5;
    const int sw_e = (tid & 31) * 2;
    const double* wg = Wt + (size_t)(k0 + sw_k) * NEXP + sw_e;

    float2  px = *(const float2*)xg;
    double2 pw = *(const double2*)wg;

    for (int c = 0; c < KSEG / 16; ++c) {
        __syncthreads();
        {
            double2 xv; xv.x = (double)px.x; xv.y = (double)px.y;
            *(double2*)&xs[sx_tok][sx_k] = xv;
            *(double2*)&wsh[sw_k][sw_e]  = pw;
        }
        __syncthreads();
        if (c + 1 < KSEG / 16) {
            px = *(const float2*)(xg + (c + 1) * 16);
            pw = *(const double2*)(wg + (size_t)(c + 1) * 16 * NEXP);
        }
        double wr_[16];
#pragma unroll
        for (int j = 0; j < 16; ++j) wr_[j] = wsh[j][lane];
#pragma unroll
        for (int t = 0; t < 8; ++t) {
            const int tr = wv * 8 + t;
#pragma unroll
            for (int kp = 0; kp < 8; ++kp) {
                double2 xv = *(const double2*)&xs[tr][kp * 2];
                acc[t] = fma(xv.x, wr_[kp * 2],     acc[t]);
                acc[t] = fma(xv.y, wr_[kp * 2 + 1], acc[t]);
            }
        }
    }

    double* pb = part + ((size_t)ks * N_TOK + tok0 + wv * 8) * NEXP + lane;
#pragma unroll
    for (int t = 0; t < 8; ++t)
        pb[(size_t)t * NEXP] = acc[t];
}

// Top-k (proven): coalesced stage -> f32-score argmax ladder, ties -> min idx.
__global__ __launch_bounds__(256) void topk_kernel(const double* __restrict__ part,
                                                   float* __restrict__ outIdx,
                                                   float* __restrict__ outW,
                                                   float* __restrict__ stats) {
    __shared__ float sc_s[32][65];
    __shared__ float lds_counts[NEXP];
    __shared__ float psum_part[4][NEXP];
    const int tid  = threadIdx.x;
    const int lane = tid & 63;
    const int w    = tid >> 6;
    if (tid < NEXP) lds_counts[tid] = 0.f;

    const int t0 = blockIdx.x * 32;
#pragma unroll
    for (int p = 0; p < 8; ++p) {
        const int idx = p * 256 + tid;
        const int t   = idx >> 6;
        const int e   = idx & 63;
        const double* pp = part + ((size_t)(t0 + t)) * NEXP + e;
        double l = (pp[0] + pp[(size_t)N_TOK * NEXP]) +
                   (pp[2 * (size_t)N_TOK * NEXP] + pp[3 * (size_t)N_TOK * NEXP]);
        sc_s[t][e] = (float)(1.0 / (1.0 + exp(-l)));
    }
    __syncthreads();

    float ps = 0.f;
    for (int i = 0; i < 8; ++i) {
        const int tloc = w * 8 + i;
        const int t    = t0 + tloc;
        float s = sc_s[tloc][lane];

        float rs = s;
#pragma unroll
        for (int off = 32; off; off >>= 1) rs += __shfl_xor(rs, off);
        ps += s / (rs + 1e-9f);

        float cur = s;
        float denom = 0.f;
        int   wi = 0;
        float wv = 0.f;
#pragma unroll
        for (int k = 0; k < TOPK; ++k) {
            float m = cur; int mi = lane;
#pragma unroll
            for (int off = 32; off; off >>= 1) {
                float om = __shfl_xor(m, off);
                int   oi = __shfl_xor(mi, off);
                if (om > m || (om == m && oi < mi)) { m = om; mi = oi; }
            }
            denom += m;
            if (lane == k)  { wi = mi; wv = m; }
            if (lane == mi) cur = -1e30f;
        }
        if (lane < TOPK) {
            outIdx[(size_t)t * TOPK + lane] = (float)wi;
            outW  [(size_t)t * TOPK + lane] = wv / (denom + 1e-9f);
            atomicAdd(&lds_counts[wi], 1.f);
        }
    }
    psum_part[w][lane] = ps;
    __syncthreads();
    if (tid < NEXP) {
        float tot = psum_part[0][tid] + psum_part[1][tid] +
                    psum_part[2][tid] + psum_part[3][tid];
        atomicAdd(&stats[tid], tot);
        atomicAdd(&stats[NEXP + tid], lds_counts[tid]);
    }
}

__global__ void aux_kernel(const float* __restrict__ stats, float* __restrict__ out) {
    const int e = threadIdx.x;
    float prob = stats[e] / (float)N_TOK;
    float cnt  = stats[NEXP + e];
    float loadf = cnt / ((float)N_TOK * TOPK);
    float S = prob;
#pragma unroll
    for (int off = 32; off; off >>= 1) S += __shfl_xor(S, off);
    float pn = prob / (S + 1e-9f);
    float v  = loadf * pn;
#pragma unroll
    for (int off = 32; off; off >>= 1) v += __shfl_xor(v, off);
    if (e == 0) out[2 * N_TOK * TOPK] = 0.001f * v * (float)NEXP;
}

extern "C" void kernel_launch(void* const* d_in, const int* in_sizes, int n_in,
                              void* d_out, int out_size, void* d_ws, size_t ws_size,
                              hipStream_t stream) {
    (void)in_sizes; (void)n_in; (void)out_size; (void)ws_size;
    const float* X = (const float*)d_in[0];
    const float* W = (const float*)d_in[1];
    float* out = (float*)d_out;
    char*  ws  = (char*)d_ws;
    double* part  = (double*)(ws + PART_OFF);
    double* Wt    = (double*)(ws + WT_OFF);
    float*  stats = (float*)(ws + STATS_OFF);
    int*    flag  = (int*)(stats + 128);

    hipMemsetAsync(stats, 0, 132 * sizeof(float), stream);
    conv_wt_kernel<<<512, 256, 0, stream>>>(W, Wt);
    mfma_probe_kernel<<<1, 64, 0, stream>>>(flag);
    gemm_mfma_kernel<<<1024, 256, 0, stream>>>(X, Wt, flag, part);
    gemm_valu_kernel<<<1024, 512, 0, stream>>>(X, Wt, flag, part);
    topk_kernel<<<512, 256, 0, stream>>>(part, out, out + N_TOK * TOPK, stats);
    aux_kernel<<<1, 64, 0, stream>>>(stats, out);
}